// Round 1
// baseline (287.090 us; speedup 1.0000x reference)
//
#include <hip/hip_runtime.h>

// Problem constants (B=32, N=256, D=256 -> M=8192)
#define M_ROWS 8192
#define D_DIM  256
#define TILE   128
#define BK     64
#define LDK    72   // 64 + 8 pad bf16 elems; row stride 144 B (16B aligned, 2-way-free banks)

typedef __attribute__((ext_vector_type(8))) short  short8;   // 8 bf16 = 4 VGPRs
typedef __attribute__((ext_vector_type(4))) float  floatx4;  // MFMA C/D

__device__ inline unsigned short f2bf(float f) {
    union { float f; unsigned int u; } v; v.f = f;
    unsigned int u = v.u;
    u = (u + 0x7fffu + ((u >> 16) & 1u)) >> 16;   // RNE
    return (unsigned short)u;
}

// Kernel 1: L2-normalize each row of a/v (fp32) and store as bf16.
// block = 256 threads = 4 waves; one wave per row (64 lanes x float4 = 256 elems).
__global__ void normalize_kernel(const float* __restrict__ af, const float* __restrict__ vf,
                                 unsigned short* __restrict__ aB, unsigned short* __restrict__ vB)
{
    const int wave = threadIdx.x >> 6, lane = threadIdx.x & 63;
    int row = blockIdx.x * 4 + wave;          // 0..16383
    const float* src;
    unsigned short* dst;
    if (row < M_ROWS) { src = af + (size_t)row * D_DIM;            dst = aB + (size_t)row * D_DIM; }
    else              { src = vf + (size_t)(row - M_ROWS) * D_DIM; dst = vB + (size_t)(row - M_ROWS) * D_DIM; }
    float4 x = *(const float4*)(src + lane * 4);
    float ss = x.x*x.x + x.y*x.y + x.z*x.z + x.w*x.w;
    #pragma unroll
    for (int m = 1; m < 64; m <<= 1) ss += __shfl_xor(ss, m, 64);
    float scale = 1.0f / fmaxf(sqrtf(ss), 1e-12f);
    ushort4 o;
    o.x = f2bf(x.x * scale); o.y = f2bf(x.y * scale);
    o.z = f2bf(x.z * scale); o.w = f2bf(x.w * scale);
    *(ushort4*)(dst + lane * 4) = o;
}

// Kernel 2: fused GEMM (sim = aB @ vB^T / TEMP), exp, label-class partial sums.
// Grid (64,64); block 256 = 4 waves. Block tile 128x128; wave owns 32 rows x 128 cols
// = 2 x 8 grid of 16x16x32 bf16 MFMA tiles.
// Accumulates: S0[i] = sum_{j: lv_j==0} e_ij, S1[i] = sum_{j: lv_j==1} e_ij,
//              T0[j] = sum_{i: la_i==0} e_ij, T1[j] = sum_{i: la_i==1} e_ij.
__global__ __launch_bounds__(256) void gemm_loss_kernel(
    const unsigned short* __restrict__ aB, const unsigned short* __restrict__ vB,
    const int* __restrict__ la, const int* __restrict__ lv,
    float* __restrict__ S0, float* __restrict__ S1,
    float* __restrict__ T0, float* __restrict__ T1)
{
    __shared__ unsigned short lA[TILE * LDK];   // 18432 B
    __shared__ unsigned short lV[TILE * LDK];   // 18432 B

    const int tid  = threadIdx.x;
    const int wave = tid >> 6, lane = tid & 63;
    const int quad = lane >> 4, l16 = lane & 15;
    const int i0 = blockIdx.x * TILE, j0 = blockIdx.y * TILE;

    // staging assignment: thread t loads 32 contiguous bf16 (64 B) of one row
    const int srow = tid >> 1;            // 0..127
    const int scol = (tid & 1) * 32;      // 0 or 32
    const unsigned short* gA = aB + (size_t)(i0 + srow) * D_DIM + scol;
    const unsigned short* gV = vB + (size_t)(j0 + srow) * D_DIM + scol;
    unsigned short* sAp = lA + srow * LDK + scol;
    unsigned short* sVp = lV + srow * LDK + scol;

    floatx4 acc[2][8] = {};

    #pragma unroll
    for (int ks = 0; ks < D_DIM / BK; ++ks) {   // 4 K-steps
        uint4 ta[4], tv[4];
        #pragma unroll
        for (int c = 0; c < 4; ++c) {
            ta[c] = *(const uint4*)(gA + ks * BK + c * 8);
            tv[c] = *(const uint4*)(gV + ks * BK + c * 8);
        }
        __syncthreads();                  // previous compute done before overwrite
        #pragma unroll
        for (int c = 0; c < 4; ++c) {
            *(uint4*)(sAp + c * 8) = ta[c];
            *(uint4*)(sVp + c * 8) = tv[c];
        }
        __syncthreads();
        #pragma unroll
        for (int kk = 0; kk < 2; ++kk) {  // two MFMA K=32 steps per BK=64
            const int ko = kk * 32 + quad * 8;
            short8 afr[2], bfr[8];
            afr[0] = *(const short8*)&lA[(wave * 32 +      l16) * LDK + ko];
            afr[1] = *(const short8*)&lA[(wave * 32 + 16 + l16) * LDK + ko];
            #pragma unroll
            for (int jt = 0; jt < 8; ++jt)
                bfr[jt] = *(const short8*)&lV[(jt * 16 + l16) * LDK + ko];
            #pragma unroll
            for (int it = 0; it < 2; ++it)
                #pragma unroll
                for (int jt = 0; jt < 8; ++jt)
                    acc[it][jt] = __builtin_amdgcn_mfma_f32_16x16x32_bf16(
                        afr[it], bfr[jt], acc[it][jt], 0, 0, 0);
        }
    }

    // ---- epilogue: exp + class-partial accumulation ----
    const int baseRow = i0 + wave * 32;
    float laf[2][4];
    #pragma unroll
    for (int it = 0; it < 2; ++it)
        #pragma unroll
        for (int r = 0; r < 4; ++r)
            laf[it][r] = (float)la[baseRow + it * 16 + quad * 4 + r];
    float lvf[8];
    #pragma unroll
    for (int jt = 0; jt < 8; ++jt)
        lvf[jt] = (float)lv[j0 + jt * 16 + l16];

    float rs0[2][4] = {}, rs1[2][4] = {};
    float ct0[8] = {}, ct1[8] = {};
    const float INV_TEMP = 1.0f / 0.07f;
    #pragma unroll
    for (int it = 0; it < 2; ++it) {
        #pragma unroll
        for (int jt = 0; jt < 8; ++jt) {
            #pragma unroll
            for (int r = 0; r < 4; ++r) {
                float e = __expf(acc[it][jt][r] * INV_TEMP);
                float p = e * lvf[jt];       // class-1 col part
                rs1[it][r] += p;
                rs0[it][r] += e - p;
                float q = e * laf[it][r];    // class-1 row part
                ct1[jt] += q;
                ct0[jt] += e - q;
            }
        }
    }

    // row sums: reduce over the quad's 16 lanes (cols), then atomicAdd per row
    #pragma unroll
    for (int it = 0; it < 2; ++it) {
        #pragma unroll
        for (int r = 0; r < 4; ++r) {
            float s0 = rs0[it][r], s1 = rs1[it][r];
            #pragma unroll
            for (int m = 1; m < 16; m <<= 1) {
                s0 += __shfl_xor(s0, m, 64);
                s1 += __shfl_xor(s1, m, 64);
            }
            if (l16 == 0) {
                int i = baseRow + it * 16 + quad * 4 + r;
                atomicAdd(&S0[i], s0);
                atomicAdd(&S1[i], s1);
            }
        }
    }

    // col sums: reduce over quads within wave, combine 4 waves via LDS, one atomic per (col,cls)
    #pragma unroll
    for (int jt = 0; jt < 8; ++jt) {
        float t0 = ct0[jt], t1 = ct1[jt];
        t0 += __shfl_xor(t0, 16, 64); t0 += __shfl_xor(t0, 32, 64);
        t1 += __shfl_xor(t1, 16, 64); t1 += __shfl_xor(t1, 32, 64);
        ct0[jt] = t0; ct1[jt] = t1;
    }
    __syncthreads();                         // all waves done reading lA/lV
    float* colbuf = (float*)lA;              // [wave][cls][128] = 4 KB, reuse staging LDS
    if (quad == 0) {
        #pragma unroll
        for (int jt = 0; jt < 8; ++jt) {
            colbuf[(wave * 2 + 0) * TILE + jt * 16 + l16] = ct0[jt];
            colbuf[(wave * 2 + 1) * TILE + jt * 16 + l16] = ct1[jt];
        }
    }
    __syncthreads();
    {
        int c = tid & 127;
        int cls = tid >> 7;
        float s = colbuf[(0 * 2 + cls) * TILE + c] + colbuf[(1 * 2 + cls) * TILE + c]
                + colbuf[(2 * 2 + cls) * TILE + c] + colbuf[(3 * 2 + cls) * TILE + c];
        atomicAdd((cls ? T1 : T0) + (j0 + c), s);
    }
}

// Kernel 3: final loss from the 4 accumulator arrays.
__global__ void finalize_kernel(const float* __restrict__ S0, const float* __restrict__ S1,
                                const float* __restrict__ T0, const float* __restrict__ T1,
                                const int* __restrict__ la, const int* __restrict__ lv,
                                float* __restrict__ out)
{
    float sA = 0.f, cA = 0.f, sV = 0.f, cV = 0.f;
    for (int i = threadIdx.x; i < M_ROWS; i += 256) {
        float num = la[i] ? S1[i] : 0.1f * S0[i];
        float den = S0[i] + S1[i];
        if (num > 0.f) { sA += logf((num + 1e-8f) / (den + 1e-8f)); cA += 1.f; }
        float numv = lv[i] ? T1[i] : 0.1f * T0[i];
        float denv = T0[i] + T1[i];
        if (numv > 0.f) { sV += logf((numv + 1e-8f) / (denv + 1e-8f)); cV += 1.f; }
    }
    #pragma unroll
    for (int m = 1; m < 64; m <<= 1) {
        sA += __shfl_xor(sA, m, 64); cA += __shfl_xor(cA, m, 64);
        sV += __shfl_xor(sV, m, 64); cV += __shfl_xor(cV, m, 64);
    }
    __shared__ float red[4][4];
    int wave = threadIdx.x >> 6, lane = threadIdx.x & 63;
    if (lane == 0) { red[wave][0] = sA; red[wave][1] = cA; red[wave][2] = sV; red[wave][3] = cV; }
    __syncthreads();
    if (threadIdx.x == 0) {
        float SA = 0.f, CA = 0.f, SV = 0.f, CV = 0.f;
        for (int w = 0; w < 4; ++w) {
            SA += red[w][0]; CA += red[w][1]; SV += red[w][2]; CV += red[w][3];
        }
        float lossA = -SA / fmaxf(CA, 1.f);
        float lossV = -SV / fmaxf(CV, 1.f);
        out[0] = 0.5f * (lossA + lossV);
    }
}

extern "C" void kernel_launch(void* const* d_in, const int* in_sizes, int n_in,
                              void* d_out, int out_size, void* d_ws, size_t ws_size,
                              hipStream_t stream)
{
    const float* af = (const float*)d_in[0];
    const float* vf = (const float*)d_in[1];
    const int*   la = (const int*)d_in[2];
    const int*   lv = (const int*)d_in[3];
    float* out = (float*)d_out;

    char* ws = (char*)d_ws;
    unsigned short* aB = (unsigned short*)ws;                         // 4 MiB
    unsigned short* vB = (unsigned short*)(ws + 4u * 1024u * 1024u);  // 4 MiB
    float* S0 = (float*)(ws + 8u * 1024u * 1024u);                    // 4 x 32 KiB
    float* S1 = S0 + M_ROWS;
    float* T0 = S1 + M_ROWS;
    float* T1 = T0 + M_ROWS;

    hipMemsetAsync(S0, 0, 4 * M_ROWS * sizeof(float), stream);
    normalize_kernel<<<(2 * M_ROWS) / 4, 256, 0, stream>>>(af, vf, aB, vB);
    dim3 grid(M_ROWS / TILE, M_ROWS / TILE);   // 64 x 64
    gemm_loss_kernel<<<grid, 256, 0, stream>>>(aB, vB, la, lv, S0, S1, T0, T1);
    finalize_kernel<<<1, 256, 0, stream>>>(S0, S1, T0, T1, la, lv, out);
}

// Round 2
// 242.550 us; speedup vs baseline: 1.1836x; 1.1836x over previous
//
#include <hip/hip_runtime.h>

// Problem constants (B=32, N=256, D=256 -> M=8192)
#define M_ROWS 8192
#define D_DIM  256
#define TILE   128
#define BK     64
#define LDK    72   // 64 + 8 pad bf16 elems; row stride 144 B (16B aligned, 2-way-free banks)
#define NBLK   (M_ROWS / TILE)   // 64 tile-blocks per dimension

typedef __attribute__((ext_vector_type(8))) short  short8;   // 8 bf16 = 4 VGPRs
typedef __attribute__((ext_vector_type(4))) float  floatx4;  // MFMA C/D

__device__ inline unsigned short f2bf(float f) {
    union { float f; unsigned int u; } v; v.f = f;
    unsigned int u = v.u;
    u = (u + 0x7fffu + ((u >> 16) & 1u)) >> 16;   // RNE
    return (unsigned short)u;
}

// Kernel 1: L2-normalize each row of a/v (fp32) and store as bf16.
// block = 256 threads = 4 waves; one wave per row (64 lanes x float4 = 256 elems).
__global__ void normalize_kernel(const float* __restrict__ af, const float* __restrict__ vf,
                                 unsigned short* __restrict__ aB, unsigned short* __restrict__ vB)
{
    const int wave = threadIdx.x >> 6, lane = threadIdx.x & 63;
    int row = blockIdx.x * 4 + wave;          // 0..16383
    const float* src;
    unsigned short* dst;
    if (row < M_ROWS) { src = af + (size_t)row * D_DIM;            dst = aB + (size_t)row * D_DIM; }
    else              { src = vf + (size_t)(row - M_ROWS) * D_DIM; dst = vB + (size_t)(row - M_ROWS) * D_DIM; }
    float4 x = *(const float4*)(src + lane * 4);
    float ss = x.x*x.x + x.y*x.y + x.z*x.z + x.w*x.w;
    #pragma unroll
    for (int m = 1; m < 64; m <<= 1) ss += __shfl_xor(ss, m, 64);
    float scale = 1.0f / fmaxf(sqrtf(ss), 1e-12f);
    ushort4 o;
    o.x = f2bf(x.x * scale); o.y = f2bf(x.y * scale);
    o.z = f2bf(x.z * scale); o.w = f2bf(x.w * scale);
    *(ushort4*)(dst + lane * 4) = o;
}

// Kernel 2: fused GEMM (sim = aB @ vB^T / TEMP), exp, label-class partial sums.
// Grid (64,64); block 256 = 4 waves. Block tile 128x128; wave owns 32 rows x 128 cols.
// NO global atomics: block (bx,by) writes
//   rowPart[by][i0+rl][cls]  (cls-partial sums over this block's 128 cols)
//   colPart[bx][j0+cl][cls]  (cls-partial sums over this block's 128 rows)
__global__ __launch_bounds__(256) void gemm_loss_kernel(
    const unsigned short* __restrict__ aB, const unsigned short* __restrict__ vB,
    const int* __restrict__ la, const int* __restrict__ lv,
    float* __restrict__ rowPart, float* __restrict__ colPart)
{
    __shared__ unsigned short lA[TILE * LDK];   // 18432 B
    __shared__ unsigned short lV[TILE * LDK];   // 18432 B

    const int tid  = threadIdx.x;
    const int wave = tid >> 6, lane = tid & 63;
    const int quad = lane >> 4, l16 = lane & 15;
    const int bx = blockIdx.x, by = blockIdx.y;
    const int i0 = bx * TILE, j0 = by * TILE;

    // staging assignment: thread t loads 32 contiguous bf16 (64 B) of one row
    const int srow = tid >> 1;            // 0..127
    const int scol = (tid & 1) * 32;      // 0 or 32
    const unsigned short* gA = aB + (size_t)(i0 + srow) * D_DIM + scol;
    const unsigned short* gV = vB + (size_t)(j0 + srow) * D_DIM + scol;
    unsigned short* sAp = lA + srow * LDK + scol;
    unsigned short* sVp = lV + srow * LDK + scol;

    floatx4 acc[2][8] = {};

    #pragma unroll
    for (int ks = 0; ks < D_DIM / BK; ++ks) {   // 4 K-steps
        uint4 ta[4], tv[4];
        #pragma unroll
        for (int c = 0; c < 4; ++c) {
            ta[c] = *(const uint4*)(gA + ks * BK + c * 8);
            tv[c] = *(const uint4*)(gV + ks * BK + c * 8);
        }
        __syncthreads();                  // previous compute done before overwrite
        #pragma unroll
        for (int c = 0; c < 4; ++c) {
            *(uint4*)(sAp + c * 8) = ta[c];
            *(uint4*)(sVp + c * 8) = tv[c];
        }
        __syncthreads();
        #pragma unroll
        for (int kk = 0; kk < 2; ++kk) {  // two MFMA K=32 steps per BK=64
            const int ko = kk * 32 + quad * 8;
            short8 afr[2], bfr[8];
            afr[0] = *(const short8*)&lA[(wave * 32 +      l16) * LDK + ko];
            afr[1] = *(const short8*)&lA[(wave * 32 + 16 + l16) * LDK + ko];
            #pragma unroll
            for (int jt = 0; jt < 8; ++jt)
                bfr[jt] = *(const short8*)&lV[(jt * 16 + l16) * LDK + ko];
            #pragma unroll
            for (int it = 0; it < 2; ++it)
                #pragma unroll
                for (int jt = 0; jt < 8; ++jt)
                    acc[it][jt] = __builtin_amdgcn_mfma_f32_16x16x32_bf16(
                        afr[it], bfr[jt], acc[it][jt], 0, 0, 0);
        }
    }

    // ---- epilogue: exp + class-partial accumulation ----
    // C/D layout (16x16x32): col = l16, row = quad*4 + r (within each 16x16 tile)
    const int baseRow = i0 + wave * 32;
    float laf[2][4];
    #pragma unroll
    for (int it = 0; it < 2; ++it)
        #pragma unroll
        for (int r = 0; r < 4; ++r)
            laf[it][r] = (float)la[baseRow + it * 16 + quad * 4 + r];
    float lvf[8];
    #pragma unroll
    for (int jt = 0; jt < 8; ++jt)
        lvf[jt] = (float)lv[j0 + jt * 16 + l16];

    float rs0[2][4] = {}, rs1[2][4] = {};
    float ct0[8] = {}, ct1[8] = {};
    const float INV_TEMP = 1.0f / 0.07f;
    #pragma unroll
    for (int it = 0; it < 2; ++it) {
        #pragma unroll
        for (int jt = 0; jt < 8; ++jt) {
            #pragma unroll
            for (int r = 0; r < 4; ++r) {
                float e = __expf(acc[it][jt][r] * INV_TEMP);
                float p = e * lvf[jt];       // class-1 col part
                rs1[it][r] += p;
                rs0[it][r] += e - p;
                float q = e * laf[it][r];    // class-1 row part
                ct1[jt] += q;
                ct0[jt] += e - q;
            }
        }
    }

    // col sums: reduce over quads within wave (register-only)
    #pragma unroll
    for (int jt = 0; jt < 8; ++jt) {
        float t0 = ct0[jt], t1 = ct1[jt];
        t0 += __shfl_xor(t0, 16, 64); t0 += __shfl_xor(t0, 32, 64);
        t1 += __shfl_xor(t1, 16, 64); t1 += __shfl_xor(t1, 32, 64);
        ct0[jt] = t0; ct1[jt] = t1;
    }

    __syncthreads();                         // all waves done reading lA/lV
    float* rowbuf = (float*)lA;              // [128][2] = 1 KB
    float* colbuf = (float*)lA + 256;        // [4 waves][2 cls][128] = 4 KB

    // row sums: reduce over the quad's 16 lanes (cols), stage in LDS
    #pragma unroll
    for (int it = 0; it < 2; ++it) {
        #pragma unroll
        for (int r = 0; r < 4; ++r) {
            float s0 = rs0[it][r], s1 = rs1[it][r];
            #pragma unroll
            for (int m = 1; m < 16; m <<= 1) {
                s0 += __shfl_xor(s0, m, 64);
                s1 += __shfl_xor(s1, m, 64);
            }
            if (l16 == 0) {
                int rl = wave * 32 + it * 16 + quad * 4 + r;   // 0..127
                rowbuf[rl * 2 + 0] = s0;
                rowbuf[rl * 2 + 1] = s1;
            }
        }
    }
    if (quad == 0) {
        #pragma unroll
        for (int jt = 0; jt < 8; ++jt) {
            colbuf[(wave * 2 + 0) * TILE + jt * 16 + l16] = ct0[jt];
            colbuf[(wave * 2 + 1) * TILE + jt * 16 + l16] = ct1[jt];
        }
    }
    __syncthreads();

    // coalesced per-block partial writes (256 consecutive floats each)
    {
        const int rl  = tid >> 1;      // 0..127
        const int cls = tid & 1;
        rowPart[((size_t)by * M_ROWS + i0 + rl) * 2 + cls] = rowbuf[rl * 2 + cls];
        float s = colbuf[(0 * 2 + cls) * TILE + rl] + colbuf[(1 * 2 + cls) * TILE + rl]
                + colbuf[(2 * 2 + cls) * TILE + rl] + colbuf[(3 * 2 + cls) * TILE + rl];
        colPart[((size_t)bx * M_ROWS + j0 + rl) * 2 + cls] = s;
    }
}

// Kernel 3: reduce partials over the 64 tile-blocks, compute per-row/col log terms,
// emit per-block (sum, count). Blocks 0..31 = audio(rows), 32..63 = visual(cols).
__global__ __launch_bounds__(256) void reduce_kernel(
    const float* __restrict__ rowPart, const float* __restrict__ colPart,
    const int* __restrict__ la, const int* __restrict__ lv,
    float* __restrict__ blockPart)
{
    const int bid = blockIdx.x;
    const bool aside = bid < 32;
    const int idx = (aside ? bid : bid - 32) * 256 + threadIdx.x;   // row or col index
    const float* part = aside ? rowPart : colPart;
    const int* lab = aside ? la : lv;

    float s0 = 0.f, s1 = 0.f;
    #pragma unroll 4
    for (int b = 0; b < NBLK; ++b) {
        float2 p = *(const float2*)(part + ((size_t)b * M_ROWS + idx) * 2);
        s0 += p.x; s1 += p.y;
    }
    float num = lab[idx] ? s1 : 0.1f * s0;
    float den = s0 + s1;
    float lg = 0.f, cnt = 0.f;
    if (num > 0.f) { lg = logf((num + 1e-8f) / (den + 1e-8f)); cnt = 1.f; }

    #pragma unroll
    for (int m = 1; m < 64; m <<= 1) {
        lg  += __shfl_xor(lg,  m, 64);
        cnt += __shfl_xor(cnt, m, 64);
    }
    __shared__ float red[4][2];
    const int w = threadIdx.x >> 6, ln = threadIdx.x & 63;
    if (ln == 0) { red[w][0] = lg; red[w][1] = cnt; }
    __syncthreads();
    if (threadIdx.x == 0) {
        blockPart[bid * 2 + 0] = red[0][0] + red[1][0] + red[2][0] + red[3][0];
        blockPart[bid * 2 + 1] = red[0][1] + red[1][1] + red[2][1] + red[3][1];
    }
}

// Kernel 4: final scalar from 64 block partials.
__global__ void finalize_kernel(const float* __restrict__ blockPart, float* __restrict__ out)
{
    if (threadIdx.x == 0) {
        float sA = 0.f, cA = 0.f, sV = 0.f, cV = 0.f;
        for (int b = 0; b < 32; ++b)  { sA += blockPart[b * 2]; cA += blockPart[b * 2 + 1]; }
        for (int b = 32; b < 64; ++b) { sV += blockPart[b * 2]; cV += blockPart[b * 2 + 1]; }
        float lossA = -sA / fmaxf(cA, 1.f);
        float lossV = -sV / fmaxf(cV, 1.f);
        out[0] = 0.5f * (lossA + lossV);
    }
}

extern "C" void kernel_launch(void* const* d_in, const int* in_sizes, int n_in,
                              void* d_out, int out_size, void* d_ws, size_t ws_size,
                              hipStream_t stream)
{
    const float* af = (const float*)d_in[0];
    const float* vf = (const float*)d_in[1];
    const int*   la = (const int*)d_in[2];
    const int*   lv = (const int*)d_in[3];
    float* out = (float*)d_out;

    char* ws = (char*)d_ws;
    unsigned short* aB = (unsigned short*)ws;                          // 4 MiB
    unsigned short* vB = (unsigned short*)(ws + 4ull * 1024 * 1024);   // 4 MiB
    float* rowPart   = (float*)(ws +  8ull * 1024 * 1024);             // 4 MiB [64][8192][2]
    float* colPart   = (float*)(ws + 12ull * 1024 * 1024);             // 4 MiB [64][8192][2]
    float* blockPart = (float*)(ws + 16ull * 1024 * 1024);             // 512 B

    normalize_kernel<<<(2 * M_ROWS) / 4, 256, 0, stream>>>(af, vf, aB, vB);
    dim3 grid(NBLK, NBLK);   // 64 x 64
    gemm_loss_kernel<<<grid, 256, 0, stream>>>(aB, vB, la, lv, rowPart, colPart);
    reduce_kernel<<<64, 256, 0, stream>>>(rowPart, colPart, la, lv, blockPart);
    finalize_kernel<<<1, 64, 0, stream>>>(blockPart, out);
}

// Round 3
// 142.400 us; speedup vs baseline: 2.0161x; 1.7033x over previous
//
#include <hip/hip_runtime.h>

// Problem constants (B=32, N=256, D=256 -> M=8192)
#define M_ROWS 8192
#define D_DIM  256
#define TILE   128
#define BK     64                 // K-slab per stage step: 64 bf16 = 128 B = 8 x 16B chunks
#define NBLK   (M_ROWS / TILE)    // 64 tile-blocks per dimension

// Fold 1/TEMP * log2(e) into normalization: acc = log2(e)*sim/TEMP, e = exp2(acc)
#define ALPHA  4.53982478f        // sqrt(log2(e)/0.07)

typedef __attribute__((ext_vector_type(8))) short  short8;   // 8 bf16 = 4 VGPRs
typedef __attribute__((ext_vector_type(4))) float  floatx4;  // MFMA C/D

__device__ inline unsigned short f2bf(float f) {
    union { float f; unsigned int u; } v; v.f = f;
    unsigned int u = v.u;
    u = (u + 0x7fffu + ((u >> 16) & 1u)) >> 16;   // RNE
    return (unsigned short)u;
}

__device__ inline float fast_exp2(float x) {
#if __has_builtin(__builtin_amdgcn_exp2f)
    return __builtin_amdgcn_exp2f(x);
#else
    return exp2f(x);
#endif
}

// async 16B/lane global->LDS DMA; lds dest is wave-uniform base + lane*16
__device__ inline void async_copy16(const void* gptr, void* lptr) {
    __builtin_amdgcn_global_load_lds(
        (const __attribute__((address_space(1))) unsigned int*)gptr,
        (__attribute__((address_space(3))) unsigned int*)lptr,
        16, 0, 0);
}

// Kernel 1: L2-normalize each row of a/v (fp32), scale by ALPHA, store bf16.
__global__ void normalize_kernel(const float* __restrict__ af, const float* __restrict__ vf,
                                 unsigned short* __restrict__ aB, unsigned short* __restrict__ vB)
{
    const int wave = threadIdx.x >> 6, lane = threadIdx.x & 63;
    int row = blockIdx.x * 4 + wave;          // 0..16383
    const float* src;
    unsigned short* dst;
    if (row < M_ROWS) { src = af + (size_t)row * D_DIM;            dst = aB + (size_t)row * D_DIM; }
    else              { src = vf + (size_t)(row - M_ROWS) * D_DIM; dst = vB + (size_t)(row - M_ROWS) * D_DIM; }
    float4 x = *(const float4*)(src + lane * 4);
    float ss = x.x*x.x + x.y*x.y + x.z*x.z + x.w*x.w;
    #pragma unroll
    for (int m = 1; m < 64; m <<= 1) ss += __shfl_xor(ss, m, 64);
    float scale = ALPHA / fmaxf(sqrtf(ss), 1e-12f);
    ushort4 o;
    o.x = f2bf(x.x * scale); o.y = f2bf(x.y * scale);
    o.z = f2bf(x.z * scale); o.w = f2bf(x.w * scale);
    *(ushort4*)(dst + lane * 4) = o;
}

// Kernel 2: fused GEMM (acc = log2e*sim/T), exp2, (total, class1) partial sums.
// Grid 4096 blocks (swizzled 16x16 supertiles); block 256 = 4 waves; tile 128x128.
// LDS: unpadded, 16B-chunk XOR swizzle (phys chunk p = logical g ^ (row&7)) applied
// on the DMA *global source* address so the LDS destination stays lane-contiguous.
// Writes per block: rowPart[by][i0+rl][{tot,c1}], colPart[bx][j0+cl][{tot,c1}].
__global__ __launch_bounds__(256) void gemm_loss_kernel(
    const unsigned short* __restrict__ aB, const unsigned short* __restrict__ vB,
    const int* __restrict__ la, const int* __restrict__ lv,
    float* __restrict__ rowPart, float* __restrict__ colPart)
{
    __shared__ unsigned short lA[TILE * BK];   // 16 KB
    __shared__ unsigned short lV[TILE * BK];   // 16 KB

    const int tid  = threadIdx.x;
    const int wave = tid >> 6, lane = tid & 63;
    const int quad = lane >> 4, l16 = lane & 15;

    // supertile swizzle: consecutive 256 blocks cover a 16x16 tile region (L2 locality)
    const int super = blockIdx.x >> 8;          // 0..15
    const int inner = blockIdx.x & 255;
    const int bx = (super & 3) * 16 + (inner & 15);
    const int by = (super >> 2) * 16 + (inner >> 4);
    const int i0 = bx * TILE, j0 = by * TILE;

    // DMA source: lane covers (row = slot*8 + lane>>3, phys chunk p = lane&7);
    // fetch logical chunk g = p ^ (row&7) so LDS phys layout is swizzled.
    const int drow = lane >> 3;                  // 0..7, == row&7 for every slot
    const int dg   = (lane & 7) ^ drow;          // logical chunk to fetch
    const unsigned short* gA0 = aB + (size_t)(i0 + drow) * D_DIM + dg * 8;
    const unsigned short* gV0 = vB + (size_t)(j0 + drow) * D_DIM + dg * 8;

    floatx4 acc[2][8] = {};

    #pragma unroll
    for (int ks = 0; ks < D_DIM / BK; ++ks) {   // 4 K-steps
        __syncthreads();                        // previous compute done before overwrite
        #pragma unroll
        for (int t = 0; t < 4; ++t) {
            const int slot = wave * 4 + t;      // 16 slots x 8 rows = 128 rows
            async_copy16(gA0 + (size_t)slot * 8 * D_DIM + ks * BK, lA + slot * 512);
            async_copy16(gV0 + (size_t)slot * 8 * D_DIM + ks * BK, lV + slot * 512);
        }
        __syncthreads();                        // drains vmcnt(0) + barrier
        #pragma unroll
        for (int kk = 0; kk < 2; ++kk) {        // two MFMA K=32 steps per BK=64
            const int gq = kk * 4 + quad;       // logical chunk of this fragment
            const int sw = l16 & 7;             // row&7 for all fragment rows
            const int pc = (gq ^ sw) * 8;       // phys chunk -> ushort offset
            short8 afr[2], bfr[8];
            afr[0] = *(const short8*)&lA[(wave * 32 +      l16) * BK + pc];
            afr[1] = *(const short8*)&lA[(wave * 32 + 16 + l16) * BK + pc];
            #pragma unroll
            for (int jt = 0; jt < 8; ++jt)
                bfr[jt] = *(const short8*)&lV[(jt * 16 + l16) * BK + pc];
            #pragma unroll
            for (int it = 0; it < 2; ++it)
                #pragma unroll
                for (int jt = 0; jt < 8; ++jt)
                    acc[it][jt] = __builtin_amdgcn_mfma_f32_16x16x32_bf16(
                        afr[it], bfr[jt], acc[it][jt], 0, 0, 0);
        }
    }

    // ---- epilogue: exp2 + (total, class1) accumulation ----
    // C/D layout (16x16x32): col = l16, row = quad*4 + r (within each 16x16 tile)
    const int baseRow = i0 + wave * 32;
    float maf[2][4];
    #pragma unroll
    for (int it = 0; it < 2; ++it)
        #pragma unroll
        for (int r = 0; r < 4; ++r)
            maf[it][r] = (float)la[baseRow + it * 16 + quad * 4 + r];
    float mvf[8];
    #pragma unroll
    for (int jt = 0; jt < 8; ++jt)
        mvf[jt] = (float)lv[j0 + jt * 16 + l16];

    float rT[2][4] = {}, r1[2][4] = {};
    float cT[8] = {}, c1[8] = {};
    #pragma unroll
    for (int it = 0; it < 2; ++it) {
        #pragma unroll
        for (int jt = 0; jt < 8; ++jt) {
            #pragma unroll
            for (int r = 0; r < 4; ++r) {
                float e = fast_exp2(acc[it][jt][r]);
                rT[it][r] += e;
                r1[it][r] = fmaf(mvf[jt], e, r1[it][r]);
                cT[jt] += e;
                c1[jt] = fmaf(maf[it][r], e, c1[jt]);
            }
        }
    }

    // col sums: reduce over quads within wave (register-only)
    #pragma unroll
    for (int jt = 0; jt < 8; ++jt) {
        float t0 = cT[jt], t1 = c1[jt];
        t0 += __shfl_xor(t0, 16, 64); t0 += __shfl_xor(t0, 32, 64);
        t1 += __shfl_xor(t1, 16, 64); t1 += __shfl_xor(t1, 32, 64);
        cT[jt] = t0; c1[jt] = t1;
    }

    __syncthreads();                         // all waves done reading lA/lV
    float* rowbuf = (float*)lA;              // [128][2] = 1 KB
    float* colbuf = (float*)lA + 256;        // [4 waves][2][128] = 4 KB

    // row sums: reduce over the quad's 16 lanes (cols), stage in LDS
    #pragma unroll
    for (int it = 0; it < 2; ++it) {
        #pragma unroll
        for (int r = 0; r < 4; ++r) {
            float s0 = rT[it][r], s1 = r1[it][r];
            #pragma unroll
            for (int m = 1; m < 16; m <<= 1) {
                s0 += __shfl_xor(s0, m, 64);
                s1 += __shfl_xor(s1, m, 64);
            }
            if (l16 == 0) {
                int rl = wave * 32 + it * 16 + quad * 4 + r;   // 0..127
                rowbuf[rl * 2 + 0] = s0;
                rowbuf[rl * 2 + 1] = s1;
            }
        }
    }
    if (quad == 0) {
        #pragma unroll
        for (int jt = 0; jt < 8; ++jt) {
            colbuf[(wave * 2 + 0) * TILE + jt * 16 + l16] = cT[jt];
            colbuf[(wave * 2 + 1) * TILE + jt * 16 + l16] = c1[jt];
        }
    }
    __syncthreads();

    // coalesced per-block partial writes (256 consecutive floats each)
    {
        const int rl  = tid >> 1;      // 0..127
        const int cls = tid & 1;
        rowPart[((size_t)by * M_ROWS + i0 + rl) * 2 + cls] = rowbuf[rl * 2 + cls];
        float s = colbuf[(0 * 2 + cls) * TILE + rl] + colbuf[(1 * 2 + cls) * TILE + rl]
                + colbuf[(2 * 2 + cls) * TILE + rl] + colbuf[(3 * 2 + cls) * TILE + rl];
        colPart[((size_t)bx * M_ROWS + j0 + rl) * 2 + cls] = s;
    }
}

// Kernel 3: reduce partials over the 64 tile-blocks, per-row/col log terms,
// emit per-block (sum, count). Blocks 0..31 = audio(rows), 32..63 = visual(cols).
// Partials are (total, class1): S1 = c1, S0 = tot - c1, denom = tot.
__global__ __launch_bounds__(256) void reduce_kernel(
    const float* __restrict__ rowPart, const float* __restrict__ colPart,
    const int* __restrict__ la, const int* __restrict__ lv,
    float* __restrict__ blockPart)
{
    const int bid = blockIdx.x;
    const bool aside = bid < 32;
    const int idx = (aside ? bid : bid - 32) * 256 + threadIdx.x;   // row or col index
    const float* part = aside ? rowPart : colPart;
    const int* lab = aside ? la : lv;

    float tot = 0.f, c1 = 0.f;
    #pragma unroll 4
    for (int b = 0; b < NBLK; ++b) {
        float2 p = *(const float2*)(part + ((size_t)b * M_ROWS + idx) * 2);
        tot += p.x; c1 += p.y;
    }
    float num = lab[idx] ? c1 : 0.1f * (tot - c1);
    float lg = 0.f, cnt = 0.f;
    if (num > 0.f) { lg = logf((num + 1e-8f) / (tot + 1e-8f)); cnt = 1.f; }

    #pragma unroll
    for (int m = 1; m < 64; m <<= 1) {
        lg  += __shfl_xor(lg,  m, 64);
        cnt += __shfl_xor(cnt, m, 64);
    }
    __shared__ float red[4][2];
    const int w = threadIdx.x >> 6, ln = threadIdx.x & 63;
    if (ln == 0) { red[w][0] = lg; red[w][1] = cnt; }
    __syncthreads();
    if (threadIdx.x == 0) {
        blockPart[bid * 2 + 0] = red[0][0] + red[1][0] + red[2][0] + red[3][0];
        blockPart[bid * 2 + 1] = red[0][1] + red[1][1] + red[2][1] + red[3][1];
    }
}

// Kernel 4: final scalar from 64 block partials.
__global__ void finalize_kernel(const float* __restrict__ blockPart, float* __restrict__ out)
{
    if (threadIdx.x == 0) {
        float sA = 0.f, cA = 0.f, sV = 0.f, cV = 0.f;
        for (int b = 0; b < 32; ++b)  { sA += blockPart[b * 2]; cA += blockPart[b * 2 + 1]; }
        for (int b = 32; b < 64; ++b) { sV += blockPart[b * 2]; cV += blockPart[b * 2 + 1]; }
        float lossA = -sA / fmaxf(cA, 1.f);
        float lossV = -sV / fmaxf(cV, 1.f);
        out[0] = 0.5f * (lossA + lossV);
    }
}

extern "C" void kernel_launch(void* const* d_in, const int* in_sizes, int n_in,
                              void* d_out, int out_size, void* d_ws, size_t ws_size,
                              hipStream_t stream)
{
    const float* af = (const float*)d_in[0];
    const float* vf = (const float*)d_in[1];
    const int*   la = (const int*)d_in[2];
    const int*   lv = (const int*)d_in[3];
    float* out = (float*)d_out;

    char* ws = (char*)d_ws;
    unsigned short* aB = (unsigned short*)ws;                          // 4 MiB
    unsigned short* vB = (unsigned short*)(ws + 4ull * 1024 * 1024);   // 4 MiB
    float* rowPart   = (float*)(ws +  8ull * 1024 * 1024);             // 4 MiB [64][8192][2]
    float* colPart   = (float*)(ws + 12ull * 1024 * 1024);             // 4 MiB [64][8192][2]
    float* blockPart = (float*)(ws + 16ull * 1024 * 1024);             // 512 B

    normalize_kernel<<<(2 * M_ROWS) / 4, 256, 0, stream>>>(af, vf, aB, vB);
    gemm_loss_kernel<<<NBLK * NBLK, 256, 0, stream>>>(aB, vB, la, lv, rowPart, colPart);
    reduce_kernel<<<64, 256, 0, stream>>>(rowPart, colPart, la, lv, blockPart);
    finalize_kernel<<<1, 64, 0, stream>>>(blockPart, out);
}

// Round 4
// 136.256 us; speedup vs baseline: 2.1070x; 1.0451x over previous
//
#include <hip/hip_runtime.h>

// Problem constants (B=32, N=256, D=256 -> M=8192)
#define M_ROWS 8192
#define D_DIM  256
#define BM     256                // block tile rows (i / audio)
#define BN     128                // block tile cols (j / visual)
#define BK     64                 // K-slab per stage step: 64 bf16 = 128 B = 8 x 16B chunks
#define NBI    (M_ROWS / BM)      // 32 i-tiles
#define NBJ    (M_ROWS / BN)      // 64 j-tiles

// Fold 1/TEMP * log2(e) into normalization: acc = log2(e)*sim/TEMP, e = exp2(acc)
#define ALPHA  4.53982478f        // sqrt(log2(e)/0.07)

typedef __attribute__((ext_vector_type(8))) short  short8;   // 8 bf16 = 4 VGPRs
typedef __attribute__((ext_vector_type(4))) float  floatx4;  // MFMA C/D

__device__ inline unsigned short f2bf(float f) {
    union { float f; unsigned int u; } v; v.f = f;
    unsigned int u = v.u;
    u = (u + 0x7fffu + ((u >> 16) & 1u)) >> 16;   // RNE
    return (unsigned short)u;
}

__device__ inline float fast_exp2(float x) {
#if __has_builtin(__builtin_amdgcn_exp2f)
    return __builtin_amdgcn_exp2f(x);
#else
    return exp2f(x);
#endif
}

// async 16B/lane global->LDS DMA; lds dest is wave-uniform base + lane*16
__device__ inline void async_copy16(const void* gptr, void* lptr) {
    __builtin_amdgcn_global_load_lds(
        (const __attribute__((address_space(1))) unsigned int*)gptr,
        (__attribute__((address_space(3))) unsigned int*)lptr,
        16, 0, 0);
}

// Kernel 1: L2-normalize each row of a/v (fp32), scale by ALPHA, store bf16.
__global__ void normalize_kernel(const float* __restrict__ af, const float* __restrict__ vf,
                                 unsigned short* __restrict__ aB, unsigned short* __restrict__ vB)
{
    const int wave = threadIdx.x >> 6, lane = threadIdx.x & 63;
    int row = blockIdx.x * 4 + wave;          // 0..16383
    const float* src;
    unsigned short* dst;
    if (row < M_ROWS) { src = af + (size_t)row * D_DIM;            dst = aB + (size_t)row * D_DIM; }
    else              { src = vf + (size_t)(row - M_ROWS) * D_DIM; dst = vB + (size_t)(row - M_ROWS) * D_DIM; }
    float4 x = *(const float4*)(src + lane * 4);
    float ss = x.x*x.x + x.y*x.y + x.z*x.z + x.w*x.w;
    #pragma unroll
    for (int m = 1; m < 64; m <<= 1) ss += __shfl_xor(ss, m, 64);
    float scale = ALPHA / fmaxf(sqrtf(ss), 1e-12f);
    ushort4 o;
    o.x = f2bf(x.x * scale); o.y = f2bf(x.y * scale);
    o.z = f2bf(x.z * scale); o.w = f2bf(x.w * scale);
    *(ushort4*)(dst + lane * 4) = o;
}

// Kernel 2: fused GEMM (acc = log2e*sim/T), exp2, (total, class1) partial sums.
// Grid 2048 blocks; block 256 = 4 waves; block tile 256x128; wave tile 64x128
// (acc[4][8]) -> LDS traffic 0.0234 B/FLOP (was 0.039: LDS-pipe-bound).
// LDS: unpadded, 16B-chunk XOR swizzle (phys chunk = logical ^ (row&7)) applied on
// the DMA *global source* address so the LDS destination stays lane-contiguous.
__global__ __launch_bounds__(256, 2) void gemm_loss_kernel(
    const unsigned short* __restrict__ aB, const unsigned short* __restrict__ vB,
    const int* __restrict__ la, const int* __restrict__ lv,
    float* __restrict__ rowPart, float* __restrict__ colPart)
{
    __shared__ unsigned short lA[BM * BK];   // 32 KB
    __shared__ unsigned short lV[BN * BK];   // 16 KB

    const int tid  = threadIdx.x;
    const int wave = tid >> 6, lane = tid & 63;
    const int quad = lane >> 4, l16 = lane & 15;

    // supertile swizzle: 8 supers x 256 inner -> 16x16 tile regions (L2 locality)
    const int super = blockIdx.x >> 8;          // 0..7
    const int inner = blockIdx.x & 255;
    const int bx = (super & 1) * 16 + (inner & 15);    // 0..31 (i-tile)
    const int by = (super >> 1) * 16 + (inner >> 4);   // 0..63 (j-tile)
    const int i0 = bx * BM, j0 = by * BN;

    // DMA source: lane covers (row = slot*8 + lane>>3, phys chunk p = lane&7);
    // fetch logical chunk g = p ^ (row&7) so LDS phys layout is swizzled.
    const int drow = lane >> 3;                  // 0..7, == row&7 for every slot
    const int dg   = (lane & 7) ^ drow;          // logical chunk to fetch
    const unsigned short* gA0 = aB + (size_t)(i0 + drow) * D_DIM + dg * 8;
    const unsigned short* gV0 = vB + (size_t)(j0 + drow) * D_DIM + dg * 8;

    floatx4 acc[4][8] = {};

    #pragma unroll
    for (int ks = 0; ks < D_DIM / BK; ++ks) {   // 4 K-steps
        __syncthreads();                        // previous compute done before overwrite
        #pragma unroll
        for (int t = 0; t < 8; ++t) {           // A: 32 slots x 8 rows = 256 rows
            const int slot = wave * 8 + t;
            async_copy16(gA0 + (size_t)slot * 8 * D_DIM + ks * BK, lA + slot * 512);
        }
        #pragma unroll
        for (int t = 0; t < 4; ++t) {           // V: 16 slots x 8 rows = 128 rows
            const int slot = wave * 4 + t;
            async_copy16(gV0 + (size_t)slot * 8 * D_DIM + ks * BK, lV + slot * 512);
        }
        __syncthreads();                        // drains vmcnt(0) + barrier
        #pragma unroll
        for (int kk = 0; kk < 2; ++kk) {        // two MFMA K=32 steps per BK=64
            const int pc = ((kk * 4 + quad) ^ (l16 & 7)) * 8;   // phys chunk offset
            short8 afr[4], bfr[8];
            #pragma unroll
            for (int it = 0; it < 4; ++it)
                afr[it] = *(const short8*)&lA[(wave * 64 + it * 16 + l16) * BK + pc];
            #pragma unroll
            for (int jt = 0; jt < 8; ++jt)
                bfr[jt] = *(const short8*)&lV[(jt * 16 + l16) * BK + pc];
            #pragma unroll
            for (int it = 0; it < 4; ++it)
                #pragma unroll
                for (int jt = 0; jt < 8; ++jt)
                    acc[it][jt] = __builtin_amdgcn_mfma_f32_16x16x32_bf16(
                        afr[it], bfr[jt], acc[it][jt], 0, 0, 0);
        }
    }

    // ---- epilogue: exp2 + (total, class1) accumulation ----
    // C/D layout (16x16x32): col = l16, row = quad*4 + r (within each 16x16 tile)
    const int baseRow = i0 + wave * 64;
    float maf[4][4];
    #pragma unroll
    for (int it = 0; it < 4; ++it)
        #pragma unroll
        for (int r = 0; r < 4; ++r)
            maf[it][r] = (float)la[baseRow + it * 16 + quad * 4 + r];
    float mvf[8];
    #pragma unroll
    for (int jt = 0; jt < 8; ++jt)
        mvf[jt] = (float)lv[j0 + jt * 16 + l16];

    float rT[4][4] = {}, r1[4][4] = {};
    float cT[8] = {}, c1[8] = {};
    #pragma unroll
    for (int it = 0; it < 4; ++it) {
        #pragma unroll
        for (int jt = 0; jt < 8; ++jt) {
            #pragma unroll
            for (int r = 0; r < 4; ++r) {
                float e = fast_exp2(acc[it][jt][r]);
                rT[it][r] += e;
                r1[it][r] = fmaf(mvf[jt], e, r1[it][r]);
                cT[jt] += e;
                c1[jt] = fmaf(maf[it][r], e, c1[jt]);
            }
        }
    }

    // col sums: reduce over quads within wave (register-only)
    #pragma unroll
    for (int jt = 0; jt < 8; ++jt) {
        float t0 = cT[jt], t1 = c1[jt];
        t0 += __shfl_xor(t0, 16, 64); t0 += __shfl_xor(t0, 32, 64);
        t1 += __shfl_xor(t1, 16, 64); t1 += __shfl_xor(t1, 32, 64);
        cT[jt] = t0; c1[jt] = t1;
    }

    __syncthreads();                         // all waves done reading lA/lV
    float* rowbuf = (float*)lA;              // [256][2] = 2 KB
    float* colbuf = (float*)lA + 512;        // [4 waves][2][128] = 4 KB

    // row sums: reduce over the quad's 16 lanes (cols), stage in LDS
    #pragma unroll
    for (int it = 0; it < 4; ++it) {
        #pragma unroll
        for (int r = 0; r < 4; ++r) {
            float s0 = rT[it][r], s1 = r1[it][r];
            #pragma unroll
            for (int m = 1; m < 16; m <<= 1) {
                s0 += __shfl_xor(s0, m, 64);
                s1 += __shfl_xor(s1, m, 64);
            }
            if (l16 == 0) {
                int rl = wave * 64 + it * 16 + quad * 4 + r;   // 0..255
                rowbuf[rl * 2 + 0] = s0;
                rowbuf[rl * 2 + 1] = s1;
            }
        }
    }
    if (quad == 0) {
        #pragma unroll
        for (int jt = 0; jt < 8; ++jt) {
            colbuf[(wave * 2 + 0) * BN + jt * 16 + l16] = cT[jt];
            colbuf[(wave * 2 + 1) * BN + jt * 16 + l16] = c1[jt];
        }
    }
    __syncthreads();

    // coalesced per-block partial writes
    {
        // rowPart: 512 floats -> one float2 per thread
        *(float2*)&rowPart[((size_t)by * M_ROWS + i0 + tid) * 2] = ((float2*)rowbuf)[tid];
        // colPart: 256 floats -> half the threads... use all: rl = tid>>1, cls = tid&1
        const int rl  = tid >> 1;      // 0..127
        const int cls = tid & 1;
        float s = colbuf[(0 * 2 + cls) * BN + rl] + colbuf[(1 * 2 + cls) * BN + rl]
                + colbuf[(2 * 2 + cls) * BN + rl] + colbuf[(3 * 2 + cls) * BN + rl];
        colPart[((size_t)bx * M_ROWS + j0 + rl) * 2 + cls] = s;
    }
}

// Kernel 3: reduce partials (rows over 64 j-slabs, cols over 32 i-slabs),
// per-row/col log terms, emit per-block (sum, count).
// Blocks 0..31 = audio(rows), 32..63 = visual(cols).
__global__ __launch_bounds__(256) void reduce_kernel(
    const float* __restrict__ rowPart, const float* __restrict__ colPart,
    const int* __restrict__ la, const int* __restrict__ lv,
    float* __restrict__ blockPart)
{
    const int bid = blockIdx.x;
    const bool aside = bid < 32;
    const int idx = (aside ? bid : bid - 32) * 256 + threadIdx.x;   // row or col index
    const float* part = aside ? rowPart : colPart;
    const int* lab = aside ? la : lv;
    const int nb = aside ? NBJ : NBI;

    float tot = 0.f, c1 = 0.f;
    #pragma unroll 4
    for (int b = 0; b < nb; ++b) {
        float2 p = *(const float2*)(part + ((size_t)b * M_ROWS + idx) * 2);
        tot += p.x; c1 += p.y;
    }
    float num = lab[idx] ? c1 : 0.1f * (tot - c1);
    float lg = 0.f, cnt = 0.f;
    if (num > 0.f) { lg = logf((num + 1e-8f) / (tot + 1e-8f)); cnt = 1.f; }

    #pragma unroll
    for (int m = 1; m < 64; m <<= 1) {
        lg  += __shfl_xor(lg,  m, 64);
        cnt += __shfl_xor(cnt, m, 64);
    }
    __shared__ float red[4][2];
    const int w = threadIdx.x >> 6, ln = threadIdx.x & 63;
    if (ln == 0) { red[w][0] = lg; red[w][1] = cnt; }
    __syncthreads();
    if (threadIdx.x == 0) {
        blockPart[bid * 2 + 0] = red[0][0] + red[1][0] + red[2][0] + red[3][0];
        blockPart[bid * 2 + 1] = red[0][1] + red[1][1] + red[2][1] + red[3][1];
    }
}

// Kernel 4: final scalar from 64 block partials (parallel: one wave, 64 lanes).
__global__ void finalize_kernel(const float* __restrict__ blockPart, float* __restrict__ out)
{
    const int lane = threadIdx.x & 63;
    float lg  = blockPart[lane * 2 + 0];
    float cnt = blockPart[lane * 2 + 1];
    // butterfly within 32-lane halves: lane 0 = audio (blocks 0..31), lane 32 = visual
    #pragma unroll
    for (int m = 1; m < 32; m <<= 1) {
        lg  += __shfl_xor(lg,  m, 64);
        cnt += __shfl_xor(cnt, m, 64);
    }
    float sA = __shfl(lg, 0, 64),  cA = __shfl(cnt, 0, 64);
    float sV = __shfl(lg, 32, 64), cV = __shfl(cnt, 32, 64);
    if (threadIdx.x == 0) {
        float lossA = -sA / fmaxf(cA, 1.f);
        float lossV = -sV / fmaxf(cV, 1.f);
        out[0] = 0.5f * (lossA + lossV);
    }
}

extern "C" void kernel_launch(void* const* d_in, const int* in_sizes, int n_in,
                              void* d_out, int out_size, void* d_ws, size_t ws_size,
                              hipStream_t stream)
{
    const float* af = (const float*)d_in[0];
    const float* vf = (const float*)d_in[1];
    const int*   la = (const int*)d_in[2];
    const int*   lv = (const int*)d_in[3];
    float* out = (float*)d_out;

    char* ws = (char*)d_ws;
    unsigned short* aB = (unsigned short*)ws;                          // 4 MiB
    unsigned short* vB = (unsigned short*)(ws + 4ull * 1024 * 1024);   // 4 MiB
    float* rowPart   = (float*)(ws +  8ull * 1024 * 1024);             // 4 MiB [64][8192][2]
    float* colPart   = (float*)(ws + 12ull * 1024 * 1024);             // 2 MiB [32][8192][2]
    float* blockPart = (float*)(ws + 14ull * 1024 * 1024);             // 512 B

    normalize_kernel<<<(2 * M_ROWS) / 4, 256, 0, stream>>>(af, vf, aB, vB);
    gemm_loss_kernel<<<NBI * NBJ, 256, 0, stream>>>(aB, vB, la, lv, rowPart, colPart);
    reduce_kernel<<<64, 256, 0, stream>>>(rowPart, colPart, la, lv, blockPart);
    finalize_kernel<<<1, 64, 0, stream>>>(blockPart, out);
}